// Round 1
// baseline (125582.690 us; speedup 1.0000x reference)
//
#include <hip/hip_runtime.h>
#include <stdint.h>
#include <math.h>

#define NN 1024
#define NB 16
#define NLOW 16

// ---------------------------------------------------------------------------
// M = 0.5*(A + A^T). Safe when A == M (each (r<=c) pair owned by one thread).
__global__ void k_symmetrize(const float* A, float* M) {
    int64_t t = (int64_t)blockIdx.x * blockDim.x + threadIdx.x;
    if (t >= (int64_t)NB * NN * NN) return;
    int b = (int)(t / (NN * NN));
    int rc = (int)(t % (NN * NN));
    int r = rc / NN, c = rc % NN;
    if (r > c) return;
    const float* Ab = A + (int64_t)b * NN * NN;
    float s = 0.5f * (Ab[(int64_t)r * NN + c] + Ab[(int64_t)c * NN + r]);
    float* Mb = M + (int64_t)b * NN * NN;
    Mb[(int64_t)r * NN + c] = s;
    Mb[(int64_t)c * NN + r] = s;
}

// ---------------------------------------------------------------------------
// Step k: build Householder reflector from x = M[k+1: , k] (LAPACK slarfg
// convention: beta = -sign(alpha)*||x||, v0 = 1). v stored in M column k and
// in compact vcomp. e[k] = beta, tau[k] = tau.
__global__ void k_reflector(float* M, float* tauA, float* eA, float* vcomp, int k) {
    int b = blockIdx.x;
    int m = NN - 1 - k;
    float* Mb = M + (int64_t)b * NN * NN;
    __shared__ double red[256];
    __shared__ float shs;
    double acc = 0.0;
    for (int i = 1 + (int)threadIdx.x; i < m; i += 256) {
        float x = Mb[(int64_t)(k + 1 + i) * NN + k];
        acc += (double)x * (double)x;
    }
    red[threadIdx.x] = acc;
    __syncthreads();
    for (int s = 128; s > 0; s >>= 1) {
        if ((int)threadIdx.x < s) red[threadIdx.x] += red[threadIdx.x + s];
        __syncthreads();
    }
    if (threadIdx.x == 0) {
        double rest = red[0];
        double alpha = (double)Mb[(int64_t)(k + 1) * NN + k];
        double tau, scale, beta;
        if (rest == 0.0) { tau = 0.0; scale = 0.0; beta = alpha; }
        else {
            double nrm = sqrt(alpha * alpha + rest);
            beta = (alpha >= 0.0) ? -nrm : nrm;
            tau = (beta - alpha) / beta;
            scale = 1.0 / (alpha - beta);
        }
        tauA[b * NN + k] = (float)tau;
        eA[b * NN + k] = (float)beta;
        shs = (float)scale;
        vcomp[b * NN + 0] = 1.0f;
    }
    __syncthreads();
    float scale = shs;
    for (int i = 1 + (int)threadIdx.x; i < m; i += 256) {
        int64_t idx = (int64_t)(k + 1 + i) * NN + k;
        float v = Mb[idx] * scale;
        Mb[idx] = v;
        vcomp[b * NN + i] = v;
    }
    if (threadIdx.x == 0) Mb[(int64_t)(k + 1) * NN + k] = 1.0f;
}

// ---------------------------------------------------------------------------
// w_raw[i] = (A_sub v)[i].  A_sub symmetric -> dot down COLUMN i (coalesced
// across threads i).
__global__ void k_matvec(const float* M, const float* vcomp, float* wv, int k) {
    int b = blockIdx.x;
    int i = blockIdx.y * blockDim.x + threadIdx.x;
    int m = NN - 1 - k;
    if (i >= m) return;
    const float* Mb = M + (int64_t)b * NN * NN;
    const float* v = vcomp + b * NN;
    const float* col = Mb + (int64_t)(k + 1) * NN + (k + 1 + i);
    float acc = 0.f;
    for (int j = 0; j < m; ++j) acc += col[(int64_t)j * NN] * v[j];
    wv[b * NN + i] = acc;
}

// ---------------------------------------------------------------------------
// w = tau*w_raw - (tau^2 * (v^T w_raw)/2) * v   (in place)
__global__ void k_wfinal(const float* vcomp, float* wv, const float* tauA, int k) {
    int b = blockIdx.x;
    int m = NN - 1 - k;
    const float* v = vcomp + b * NN;
    float* wb = wv + b * NN;
    __shared__ double red[256];
    double acc = 0.0;
    for (int i = threadIdx.x; i < (unsigned)m; i += 256) acc += (double)v[i] * (double)wb[i];
    red[threadIdx.x] = acc;
    __syncthreads();
    for (int s = 128; s > 0; s >>= 1) {
        if ((int)threadIdx.x < s) red[threadIdx.x] += red[threadIdx.x + s];
        __syncthreads();
    }
    float tau = tauA[b * NN + k];
    float c = (float)(0.5 * (double)tau * (double)tau * red[0]);
    for (int i = threadIdx.x; i < (unsigned)m; i += 256) wb[i] = tau * wb[i] - c * v[i];
}

// ---------------------------------------------------------------------------
// A_sub -= v w^T + w v^T  (full m x m, keeps both triangles)
__global__ void k_rank2(float* M, const float* vcomp, const float* wv, int k) {
    int b = blockIdx.x;
    uint32_t idx = blockIdx.y * 256u + threadIdx.x;
    int m = NN - 1 - k;
    if (idx >= (uint32_t)(m * m)) return;
    int i = (int)(idx / (uint32_t)m), j = (int)(idx % (uint32_t)m);
    const float* v = vcomp + b * NN;
    const float* wb = wv + b * NN;
    float* Mb = M + (int64_t)b * NN * NN;
    Mb[(int64_t)(k + 1 + i) * NN + (k + 1 + j)] -= v[i] * wb[j] + wb[i] * v[j];
}

// ---------------------------------------------------------------------------
__global__ void k_extract(const float* M, float* dA, float* eA) {
    int t = blockIdx.x * blockDim.x + threadIdx.x;
    if (t >= NB * NN) return;
    int b = t / NN, i = t % NN;
    dA[t] = M[(int64_t)b * NN * NN + (int64_t)i * NN + i];
    if (i == NN - 2)
        eA[b * NN + NN - 2] = M[(int64_t)b * NN * NN + (int64_t)(NN - 1) * NN + (NN - 2)];
}

// ---------------------------------------------------------------------------
// f64 Sturm bisection: thread p=(b,j) finds j-th smallest eigenvalue of T_b.
__global__ void k_bisect(const float* dA, const float* eA, double* lam, float* out) {
    int p = threadIdx.x;        // one block of 256 = NB*NLOW pairs
    int b = p >> 4, j = p & 15;
    const float* d = dA + b * NN;
    const float* e = eA + b * NN;
    double lo = 1e30, hi = -1e30;
    for (int i = 0; i < NN; ++i) {
        double di = (double)d[i];
        double r = 0.0;
        if (i > 0) r += fabs((double)e[i - 1]);
        if (i < NN - 1) r += fabs((double)e[i]);
        lo = fmin(lo, di - r);
        hi = fmax(hi, di + r);
    }
    lo -= 1e-3; hi += 1e-3;
    for (int it = 0; it < 50; ++it) {
        double x = 0.5 * (lo + hi);
        int cnt = 0;
        double q = (double)d[0] - x;
        if (q < 0.0) cnt++;
        for (int i = 1; i < NN; ++i) {
            double ei = (double)e[i - 1];
            double den = q;
            if (fabs(den) < 1e-30) den = (den < 0.0) ? -1e-30 : 1e-30;
            q = ((double)d[i] - x) - ei * ei / den;
            if (q < 0.0) cnt++;
        }
        if (cnt >= j + 1) hi = x; else lo = x;
    }
    double l = 0.5 * (lo + hi);
    lam[p] = l;
    out[b * NLOW + j] = (float)l;   // eigenvalues, ascending
}

// ---------------------------------------------------------------------------
// Inverse iteration on T (f64, partial-pivot LU a la sgttrf/sgtts2).
__global__ void k_invit(const float* dA, const float* eA, const double* lam,
                        float* vtri, double* U0, double* U1, double* U2,
                        double* LM, float* PV, double* XV) {
    int p = blockIdx.x * blockDim.x + threadIdx.x;
    if (p >= NB * NLOW) return;
    int b = p / NLOW;
    const float* d = dA + b * NN;
    const float* e = eA + b * NN;
    double lambda = lam[p];
    double* dd  = U0 + (int64_t)p * NN;
    double* du  = U1 + (int64_t)p * NN;
    double* du2 = U2 + (int64_t)p * NN;
    double* dl  = LM + (int64_t)p * NN;
    float*  pv  = PV + (int64_t)p * NN;
    double* X   = XV + (int64_t)p * NN;

    for (int i = 0; i < NN; ++i) dd[i] = (double)d[i] - lambda;
    for (int i = 0; i < NN - 1; ++i) { du[i] = (double)e[i]; dl[i] = (double)e[i]; }
    du[NN - 1] = 0.0; dl[NN - 1] = 0.0;

    for (int i = 0; i < NN - 1; ++i) {
        if (fabs(dd[i]) >= fabs(dl[i])) {
            pv[i] = 0.f;
            double fact = (dd[i] != 0.0) ? dl[i] / dd[i] : 0.0;
            dl[i] = fact;
            dd[i + 1] -= fact * du[i];
            du2[i] = 0.0;
        } else {
            pv[i] = 1.f;
            double fact = dd[i] / dl[i];
            dd[i] = dl[i];
            dl[i] = fact;
            double temp = du[i];
            du[i] = dd[i + 1];
            dd[i + 1] = temp - fact * dd[i + 1];
            if (i < NN - 2) { du2[i] = du[i + 1]; du[i + 1] = -fact * du[i + 1]; }
            else du2[i] = 0.0;
        }
    }
    for (int i = 0; i < NN; ++i)
        if (fabs(dd[i]) < 1e-300) dd[i] = (dd[i] < 0.0) ? -1e-300 : 1e-300;

    for (int i = 0; i < NN; ++i) {
        uint32_t h = ((uint32_t)i * 2654435761u) ^ ((uint32_t)p * 40503u);
        h = h * 1664525u + 1013904223u;
        X[i] = 1.0 + 1e-3 * ((double)(h & 2047) / 1024.0 - 1.0);
    }
    for (int iter = 0; iter < 2; ++iter) {
        for (int i = 0; i < NN - 1; ++i) {
            if (pv[i] == 0.f) X[i + 1] -= dl[i] * X[i];
            else { double t = X[i]; X[i] = X[i + 1]; X[i + 1] = t - dl[i] * X[i]; }
        }
        X[NN - 1] /= dd[NN - 1];
        X[NN - 2] = (X[NN - 2] - du[NN - 2] * X[NN - 1]) / dd[NN - 2];
        for (int i = NN - 3; i >= 0; --i)
            X[i] = (X[i] - du[i] * X[i + 1] - du2[i] * X[i + 2]) / dd[i];
        double nrm = 0.0;
        for (int i = 0; i < NN; ++i) nrm += X[i] * X[i];
        double inv = 1.0 / sqrt(fmax(nrm, 1e-300));
        for (int i = 0; i < NN; ++i) X[i] *= inv;
    }
    float* vt = vtri + (int64_t)p * NN;
    for (int i = 0; i < NN; ++i) vt[i] = (float)X[i];
}

// ---------------------------------------------------------------------------
// Modified Gram-Schmidt safety pass over the 16 tridiagonal eigenvectors.
__global__ void k_gs(float* vtri) {
    int b = blockIdx.x;
    float* V = vtri + (int64_t)b * NLOW * NN;
    __shared__ double red[256];
    for (int j = 0; j < NLOW; ++j) {
        float* vj = V + j * NN;
        for (int i2 = 0; i2 < j; ++i2) {
            const float* vi = V + i2 * NN;
            double acc = 0.0;
            for (int t = threadIdx.x; t < NN; t += 256) acc += (double)vi[t] * (double)vj[t];
            red[threadIdx.x] = acc; __syncthreads();
            for (int s = 128; s > 0; s >>= 1) {
                if ((int)threadIdx.x < s) red[threadIdx.x] += red[threadIdx.x + s];
                __syncthreads();
            }
            float r = (float)red[0];
            for (int t = threadIdx.x; t < NN; t += 256) vj[t] -= r * vi[t];
            __syncthreads();
        }
        double acc = 0.0;
        for (int t = threadIdx.x; t < NN; t += 256) acc += (double)vj[t] * (double)vj[t];
        red[threadIdx.x] = acc; __syncthreads();
        for (int s = 128; s > 0; s >>= 1) {
            if ((int)threadIdx.x < s) red[threadIdx.x] += red[threadIdx.x + s];
            __syncthreads();
        }
        float inv = (float)(1.0 / sqrt(fmax(red[0], 1e-300)));
        for (int t = threadIdx.x; t < NN; t += 256) vj[t] *= inv;
        __syncthreads();
    }
}

// ---------------------------------------------------------------------------
// Back-transform 8 vectors/pass through the Householder chain; canonicalize
// sign (largest |entry| positive); write output.
__global__ __launch_bounds__(512) void k_backtransform(const float* M, const float* tauA,
                                                       const float* vtri, float* out) {
    int b = blockIdx.x;
    int pass = blockIdx.y;
    int w = threadIdx.x >> 6;
    int lane = threadIdx.x & 63;
    int j = pass * 8 + w;
    __shared__ float xs[8][NN];
    __shared__ float us[NN];
    const float* Mb = M + (int64_t)b * NN * NN;
    for (int i = lane; i < NN; i += 64)
        xs[w][i] = vtri[((int64_t)b * NLOW + j) * NN + i];
    __syncthreads();
    for (int k = NN - 3; k >= 0; --k) {
        int m = NN - 1 - k;
        for (int t = threadIdx.x; t < (unsigned)m; t += 512)
            us[t] = Mb[(int64_t)(k + 1 + t) * NN + k];
        __syncthreads();
        float tauk = tauA[b * NN + k];
        float acc = 0.f;
        for (int t = lane; t < m; t += 64) acc += us[t] * xs[w][k + 1 + t];
        for (int off = 32; off > 0; off >>= 1) acc += __shfl_xor(acc, off);
        float s = tauk * acc;
        for (int t = lane; t < m; t += 64) xs[w][k + 1 + t] -= s * us[t];
        __syncthreads();
    }
    // sign canonicalization: entry of largest magnitude made positive
    float mx = -1.f; int mi = 0;
    for (int i = lane; i < NN; i += 64) {
        float a = fabsf(xs[w][i]);
        if (a > mx) { mx = a; mi = i; }
    }
    for (int off = 32; off > 0; off >>= 1) {
        float omx = __shfl_xor(mx, off);
        int omi = __shfl_xor(mi, off);
        if (omx > mx || (omx == mx && omi < mi)) { mx = omx; mi = omi; }
    }
    float sgn = (xs[w][mi] < 0.f) ? -1.f : 1.f;
    for (int i = lane; i < NN; i += 64)
        out[256 + ((int64_t)(b * NN + i)) * NLOW + j] = sgn * xs[w][i];
}

// ---------------------------------------------------------------------------
extern "C" void kernel_launch(void* const* d_in, const int* in_sizes, int n_in,
                              void* d_out, int out_size, void* d_ws, size_t ws_size,
                              hipStream_t stream) {
    const float* A = (const float*)d_in[0];
    float* out = (float*)d_out;

    char* base = (char*)d_ws;
    size_t off = 0;
    auto alloc = [&](size_t bytes) -> void* {
        void* p = (void*)(base + off);
        off = (off + bytes + 255) & ~(size_t)255;
        return p;
    };
    double* lam  = (double*)alloc(sizeof(double) * NB * NLOW);
    double* u0   = (double*)alloc(sizeof(double) * (size_t)NB * NLOW * NN);
    double* u1   = (double*)alloc(sizeof(double) * (size_t)NB * NLOW * NN);
    double* u2   = (double*)alloc(sizeof(double) * (size_t)NB * NLOW * NN);
    double* lmul = (double*)alloc(sizeof(double) * (size_t)NB * NLOW * NN);
    double* xv   = (double*)alloc(sizeof(double) * (size_t)NB * NLOW * NN);
    float* pivf  = (float*)alloc(sizeof(float) * (size_t)NB * NLOW * NN);
    float* vtri  = (float*)alloc(sizeof(float) * (size_t)NB * NLOW * NN);
    float* tau   = (float*)alloc(sizeof(float) * NB * NN);
    float* evec  = (float*)alloc(sizeof(float) * NB * NN);
    float* dvec  = (float*)alloc(sizeof(float) * NB * NN);
    float* vcomp = (float*)alloc(sizeof(float) * NB * NN);
    float* wv    = (float*)alloc(sizeof(float) * NB * NN);
    size_t small_end = off;

    float* M;
    if (ws_size >= small_end + sizeof(float) * (size_t)NB * NN * NN)
        M = (float*)alloc(sizeof(float) * (size_t)NB * NN * NN);
    else
        M = (float*)d_in[0];   // in-place fallback (harness restores d_in)

    int grid_sym = (NB * NN * NN) / 256;
    k_symmetrize<<<grid_sym, 256, 0, stream>>>(A, M);

    for (int k = 0; k <= NN - 3; ++k) {
        int m = NN - 1 - k;
        k_reflector<<<NB, 256, 0, stream>>>(M, tau, evec, vcomp, k);
        dim3 gB(NB, (m + 255) / 256);
        k_matvec<<<gB, 256, 0, stream>>>(M, vcomp, wv, k);
        k_wfinal<<<NB, 256, 0, stream>>>(vcomp, wv, tau, k);
        dim3 gD(NB, (unsigned)(((int64_t)m * m + 255) / 256));
        k_rank2<<<gD, 256, 0, stream>>>(M, vcomp, wv, k);
    }

    k_extract<<<(NB * NN + 255) / 256, 256, 0, stream>>>(M, dvec, evec);
    k_bisect<<<1, 256, 0, stream>>>(dvec, evec, lam, out);
    k_invit<<<4, 64, 0, stream>>>(dvec, evec, lam, vtri, u0, u1, u2, lmul, pivf, xv);
    k_gs<<<NB, 256, 0, stream>>>(vtri);
    dim3 gI(NB, 2);
    k_backtransform<<<gI, 512, 0, stream>>>(M, tau, vtri, out);
}

// Round 2
// 60623.889 us; speedup vs baseline: 2.0715x; 2.0715x over previous
//
#include <hip/hip_runtime.h>
#include <stdint.h>
#include <math.h>

#define NN 1024
#define NB 16
#define NLOW 16
#define PNB 32      // panel width
#define JCH 128     // symv j-chunk

// ---------------------------------------------------------------------------
// M = 0.5*(A + A^T). Safe when A == M (each (r<=c) pair owned by one thread).
__global__ void k_symmetrize(const float* A, float* M) {
    int64_t t = (int64_t)blockIdx.x * blockDim.x + threadIdx.x;
    if (t >= (int64_t)NB * NN * NN) return;
    int b = (int)(t / (NN * NN));
    int rc = (int)(t % (NN * NN));
    int r = rc / NN, c = rc % NN;
    if (r > c) return;
    const float* Ab = A + (int64_t)b * NN * NN;
    float s = 0.5f * (Ab[(int64_t)r * NN + c] + Ab[(int64_t)c * NN + r]);
    float* Mb = M + (int64_t)b * NN * NN;
    Mb[(int64_t)r * NN + c] = s;
    Mb[(int64_t)c * NN + r] = s;
}

// ---------------------------------------------------------------------------
// Panel kernel (one block per batch). For call (k0, j, do_col):
//   Phase 1 (j>0): finish W column j-1:
//     w_full = w_raw - V*(W^T v) - W*(V^T v);  w1 = tau*w_full;
//     W[:,j-1] = w1 - 0.5*tau*(w1^T v)*v
//   Phase 2 (do_col): update column k=k0+j with panel rank-2j, compute d[k],
//     Householder reflector -> tau[k], e[k]=beta, v stored to Vp and M column.
//   Phase 3: zero wv for the next symv.
// Vp/Wp layout: [b][t][i] column-major panels, i = local row (global k0+1+i).
__global__ __launch_bounds__(256) void k_panel(float* M, float* Vp, float* Wp, float* wv,
                                               float* tauA, float* eA, float* dA,
                                               int k0, int j, int do_col) {
    int b = blockIdx.x, tid = threadIdx.x;
    int m0 = NN - 1 - k0;
    float* Mb = M + (int64_t)b * NN * NN;
    __shared__ double redd[256];
    __shared__ float shc1[PNB], shc2[PNB];
    __shared__ float shvr[PNB], shwr[PNB];
    __shared__ float sh_upd[NN];
    __shared__ float shs;

    if (j > 0) {
        int jp = j - 1, kp = k0 + jp;
        const float* v = Vp + ((int64_t)b * PNB + jp) * NN;
        float* wcol = Wp + ((int64_t)b * PNB + jp) * NN;
        int ndots = 2 * jp;
        int wid = tid >> 6, lane = tid & 63;
        for (int dd = wid; dd < ndots; dd += 4) {
            int t = dd >> 1;
            const float* src = (((dd & 1) == 0) ? Wp : Vp) + ((int64_t)b * PNB + t) * NN;
            double acc = 0.0;
            for (int i = jp + lane; i < m0; i += 64) acc += (double)src[i] * (double)v[i];
            for (int off = 32; off > 0; off >>= 1) acc += __shfl_xor(acc, off);
            if (lane == 0) { if ((dd & 1) == 0) shc1[t] = (float)acc; else shc2[t] = (float)acc; }
        }
        __syncthreads();
        float taup = tauA[b * NN + kp];
        double dot = 0.0;
        for (int i = jp + tid; i < m0; i += 256) {
            float wr = wv[b * NN + i];
            for (int t = 0; t < jp; ++t)
                wr -= Vp[((int64_t)b * PNB + t) * NN + i] * shc1[t]
                    + Wp[((int64_t)b * PNB + t) * NN + i] * shc2[t];
            float w1 = taup * wr;
            wcol[i] = w1;
            dot += (double)w1 * (double)v[i];
        }
        redd[tid] = dot; __syncthreads();
        for (int s = 128; s > 0; s >>= 1) {
            if (tid < s) redd[tid] += redd[tid + s];
            __syncthreads();
        }
        float alpha = (float)(-0.5 * (double)taup * redd[0]);
        for (int i = jp + tid; i < m0; i += 256) wcol[i] += alpha * v[i];
        __syncthreads();
    }

    if (do_col) {
        int k = k0 + j;
        if (tid < j) {  // row k of panels, local row j-1
            shvr[tid] = Vp[((int64_t)b * PNB + tid) * NN + (j - 1)];
            shwr[tid] = Wp[((int64_t)b * PNB + tid) * NN + (j - 1)];
        }
        __syncthreads();
        if (tid == 0) {
            float dkk = Mb[(int64_t)k * NN + k];
            for (int t = 0; t < j; ++t) dkk -= 2.f * shvr[t] * shwr[t];
            dA[b * NN + k] = dkk;
        }
        for (int i = j + tid; i < m0; i += 256) {
            float u = Mb[(int64_t)(k0 + 1 + i) * NN + k];
            for (int t = 0; t < j; ++t)
                u -= Vp[((int64_t)b * PNB + t) * NN + i] * shwr[t]
                   + Wp[((int64_t)b * PNB + t) * NN + i] * shvr[t];
            sh_upd[i] = u;
        }
        __syncthreads();
        double acc = 0.0;
        for (int i = j + 1 + tid; i < m0; i += 256) { float x = sh_upd[i]; acc += (double)x * x; }
        redd[tid] = acc; __syncthreads();
        for (int s = 128; s > 0; s >>= 1) {
            if (tid < s) redd[tid] += redd[tid + s];
            __syncthreads();
        }
        if (tid == 0) {
            double rest = redd[0];
            double alpha = (double)sh_upd[j];
            double tau, scale, beta;
            if (rest == 0.0) { tau = 0.0; scale = 0.0; beta = alpha; }
            else {
                double nrm = sqrt(alpha * alpha + rest);
                beta = (alpha >= 0.0) ? -nrm : nrm;
                tau = (beta - alpha) / beta;
                scale = 1.0 / (alpha - beta);
            }
            tauA[b * NN + k] = (float)tau;
            eA[b * NN + k] = (float)beta;
            shs = (float)scale;
        }
        __syncthreads();
        float scale = shs;
        float* vout = Vp + ((int64_t)b * PNB + j) * NN;
        for (int i = j + tid; i < m0; i += 256) {
            float vv = (i == j) ? 1.f : sh_upd[i] * scale;
            vout[i] = vv;
            Mb[(int64_t)(k0 + 1 + i) * NN + k] = vv;   // stored reflector for backtransform
        }
        __syncthreads();
    }
    for (int i = tid; i < NN; i += 256) wv[b * NN + i] = 0.f;
}

// ---------------------------------------------------------------------------
// w_raw = A(k+1:,k+1:) * v  (panel-start trailing matrix, full storage).
// Grid: (NB, ceil(m/256), ceil(m/JCH)). Partial sums via float atomics.
__global__ __launch_bounds__(256) void k_symv(const float* M, const float* Vp, float* wv,
                                              int k0, int j) {
    int b = blockIdx.x;
    int k = k0 + j, m = NN - 1 - k, base = k + 1;
    int i = blockIdx.y * 256 + threadIdx.x;
    int jg0 = blockIdx.z * JCH;
    int jg1 = min(m, jg0 + JCH);
    __shared__ float vs[JCH];
    const float* vcol = Vp + ((int64_t)b * PNB + j) * NN;
    for (int t = threadIdx.x; t < jg1 - jg0; t += 256) vs[t] = vcol[jg0 + t + j];
    __syncthreads();
    if (i >= m) return;
    const float* Mb = M + (int64_t)b * NN * NN;
    const float* p = Mb + (int64_t)(base + jg0) * NN + base + i;
    float acc = 0.f;
    for (int jg = jg0; jg < jg1; ++jg, p += NN) acc += (*p) * vs[jg - jg0];
    atomicAdd(&wv[b * NN + i + j], acc);
}

// ---------------------------------------------------------------------------
// Trailing update A(s:,s:) -= V*W^T + W*V^T, 64x64 tiles, LDS-staged panels.
__global__ __launch_bounds__(256) void k_update(float* M, const float* Vp, const float* Wp,
                                                int k0, int nbe) {
    int b = blockIdx.x;
    int s = k0 + nbe, m2 = NN - s;
    int r0 = blockIdx.y * 64, c0 = blockIdx.z * 64;
    if (r0 >= m2 || c0 >= m2) return;
    __shared__ float Vr[PNB][64], Wr[PNB][64], Vc[PNB][64], Wc[PNB][64];
    int tid = threadIdx.x;
    int rowoff = nbe - 1;
    for (int idx = tid; idx < nbe * 64; idx += 256) {
        int t = idx >> 6, x = idx & 63;
        const float* vp = Vp + ((int64_t)b * PNB + t) * NN;
        const float* wp = Wp + ((int64_t)b * PNB + t) * NN;
        int rr = r0 + x, cc = c0 + x;
        Vr[t][x] = (rr < m2) ? vp[rowoff + rr] : 0.f;
        Wr[t][x] = (rr < m2) ? wp[rowoff + rr] : 0.f;
        Vc[t][x] = (cc < m2) ? vp[rowoff + cc] : 0.f;
        Wc[t][x] = (cc < m2) ? wp[rowoff + cc] : 0.f;
    }
    __syncthreads();
    int tx = tid & 15, ty = tid >> 4;
    float accv[4][4] = {};
    for (int t = 0; t < nbe; ++t) {
        float va[4], wa[4], vb4[4], wb4[4];
#pragma unroll
        for (int a = 0; a < 4; ++a) {
            va[a] = Vr[t][ty * 4 + a]; wa[a] = Wr[t][ty * 4 + a];
            vb4[a] = Vc[t][tx * 4 + a]; wb4[a] = Wc[t][tx * 4 + a];
        }
#pragma unroll
        for (int a = 0; a < 4; ++a)
#pragma unroll
            for (int c = 0; c < 4; ++c) accv[a][c] += va[a] * wb4[c] + wa[a] * vb4[c];
    }
    float* Mb = M + (int64_t)b * NN * NN;
    for (int a = 0; a < 4; ++a) {
        int r = r0 + ty * 4 + a;
        if (r >= m2) break;
        for (int c = 0; c < 4; ++c) {
            int cc = c0 + tx * 4 + c;
            if (cc >= m2) continue;
            int64_t ad = (int64_t)(s + r) * NN + (s + cc);
            Mb[ad] -= accv[a][c];
        }
    }
}

// ---------------------------------------------------------------------------
__global__ void k_extract2(const float* M, float* dA, float* eA) {
    int b = blockIdx.x;
    if (threadIdx.x == 0) {
        const float* Mb = M + (int64_t)b * NN * NN;
        dA[b * NN + NN - 2] = Mb[(int64_t)(NN - 2) * NN + NN - 2];
        dA[b * NN + NN - 1] = Mb[(int64_t)(NN - 1) * NN + NN - 1];
        eA[b * NN + NN - 2] = Mb[(int64_t)(NN - 1) * NN + NN - 2];
    }
}

// ---------------------------------------------------------------------------
// f64 Sturm bisection: thread p=(b,j) finds j-th smallest eigenvalue of T_b.
__global__ void k_bisect(const float* dA, const float* eA, double* lam, float* out) {
    int p = threadIdx.x;
    int b = p >> 4, j = p & 15;
    const float* d = dA + b * NN;
    const float* e = eA + b * NN;
    double lo = 1e30, hi = -1e30;
    for (int i = 0; i < NN; ++i) {
        double di = (double)d[i];
        double r = 0.0;
        if (i > 0) r += fabs((double)e[i - 1]);
        if (i < NN - 1) r += fabs((double)e[i]);
        lo = fmin(lo, di - r);
        hi = fmax(hi, di + r);
    }
    lo -= 1e-3; hi += 1e-3;
    for (int it = 0; it < 50; ++it) {
        double x = 0.5 * (lo + hi);
        int cnt = 0;
        double q = (double)d[0] - x;
        if (q < 0.0) cnt++;
        for (int i = 1; i < NN; ++i) {
            double ei = (double)e[i - 1];
            double den = q;
            if (fabs(den) < 1e-30) den = (den < 0.0) ? -1e-30 : 1e-30;
            q = ((double)d[i] - x) - ei * ei / den;
            if (q < 0.0) cnt++;
        }
        if (cnt >= j + 1) hi = x; else lo = x;
    }
    double l = 0.5 * (lo + hi);
    lam[p] = l;
    out[b * NLOW + j] = (float)l;
}

// ---------------------------------------------------------------------------
// Inverse iteration on T (f64, partial-pivot LU a la sgttrf/sgtts2).
__global__ void k_invit(const float* dA, const float* eA, const double* lam,
                        float* vtri, double* U0, double* U1, double* U2,
                        double* LM, float* PV, double* XV) {
    int p = blockIdx.x * blockDim.x + threadIdx.x;
    if (p >= NB * NLOW) return;
    int b = p / NLOW;
    const float* d = dA + b * NN;
    const float* e = eA + b * NN;
    double lambda = lam[p];
    double* dd  = U0 + (int64_t)p * NN;
    double* du  = U1 + (int64_t)p * NN;
    double* du2 = U2 + (int64_t)p * NN;
    double* dl  = LM + (int64_t)p * NN;
    float*  pv  = PV + (int64_t)p * NN;
    double* X   = XV + (int64_t)p * NN;

    for (int i = 0; i < NN; ++i) dd[i] = (double)d[i] - lambda;
    for (int i = 0; i < NN - 1; ++i) { du[i] = (double)e[i]; dl[i] = (double)e[i]; }
    du[NN - 1] = 0.0; dl[NN - 1] = 0.0;

    for (int i = 0; i < NN - 1; ++i) {
        if (fabs(dd[i]) >= fabs(dl[i])) {
            pv[i] = 0.f;
            double fact = (dd[i] != 0.0) ? dl[i] / dd[i] : 0.0;
            dl[i] = fact;
            dd[i + 1] -= fact * du[i];
            du2[i] = 0.0;
        } else {
            pv[i] = 1.f;
            double fact = dd[i] / dl[i];
            dd[i] = dl[i];
            dl[i] = fact;
            double temp = du[i];
            du[i] = dd[i + 1];
            dd[i + 1] = temp - fact * dd[i + 1];
            if (i < NN - 2) { du2[i] = du[i + 1]; du[i + 1] = -fact * du[i + 1]; }
            else du2[i] = 0.0;
        }
    }
    for (int i = 0; i < NN; ++i)
        if (fabs(dd[i]) < 1e-300) dd[i] = (dd[i] < 0.0) ? -1e-300 : 1e-300;

    for (int i = 0; i < NN; ++i) {
        uint32_t h = ((uint32_t)i * 2654435761u) ^ ((uint32_t)p * 40503u);
        h = h * 1664525u + 1013904223u;
        X[i] = 1.0 + 1e-3 * ((double)(h & 2047) / 1024.0 - 1.0);
    }
    for (int iter = 0; iter < 2; ++iter) {
        for (int i = 0; i < NN - 1; ++i) {
            if (pv[i] == 0.f) X[i + 1] -= dl[i] * X[i];
            else { double t = X[i]; X[i] = X[i + 1]; X[i + 1] = t - dl[i] * X[i]; }
        }
        X[NN - 1] /= dd[NN - 1];
        X[NN - 2] = (X[NN - 2] - du[NN - 2] * X[NN - 1]) / dd[NN - 2];
        for (int i = NN - 3; i >= 0; --i)
            X[i] = (X[i] - du[i] * X[i + 1] - du2[i] * X[i + 2]) / dd[i];
        double nrm = 0.0;
        for (int i = 0; i < NN; ++i) nrm += X[i] * X[i];
        double inv = 1.0 / sqrt(fmax(nrm, 1e-300));
        for (int i = 0; i < NN; ++i) X[i] *= inv;
    }
    float* vt = vtri + (int64_t)p * NN;
    for (int i = 0; i < NN; ++i) vt[i] = (float)X[i];
}

// ---------------------------------------------------------------------------
// Modified Gram-Schmidt safety pass over the 16 tridiagonal eigenvectors.
__global__ void k_gs(float* vtri) {
    int b = blockIdx.x;
    float* V = vtri + (int64_t)b * NLOW * NN;
    __shared__ double red[256];
    for (int j = 0; j < NLOW; ++j) {
        float* vj = V + j * NN;
        for (int i2 = 0; i2 < j; ++i2) {
            const float* vi = V + i2 * NN;
            double acc = 0.0;
            for (int t = threadIdx.x; t < NN; t += 256) acc += (double)vi[t] * (double)vj[t];
            red[threadIdx.x] = acc; __syncthreads();
            for (int s = 128; s > 0; s >>= 1) {
                if ((int)threadIdx.x < s) red[threadIdx.x] += red[threadIdx.x + s];
                __syncthreads();
            }
            float r = (float)red[0];
            for (int t = threadIdx.x; t < NN; t += 256) vj[t] -= r * vi[t];
            __syncthreads();
        }
        double acc = 0.0;
        for (int t = threadIdx.x; t < NN; t += 256) acc += (double)vj[t] * (double)vj[t];
        red[threadIdx.x] = acc; __syncthreads();
        for (int s = 128; s > 0; s >>= 1) {
            if ((int)threadIdx.x < s) red[threadIdx.x] += red[threadIdx.x + s];
            __syncthreads();
        }
        float inv = (float)(1.0 / sqrt(fmax(red[0], 1e-300)));
        for (int t = threadIdx.x; t < NN; t += 256) vj[t] *= inv;
        __syncthreads();
    }
}

// ---------------------------------------------------------------------------
// Back-transform 8 vectors/pass through the Householder chain; canonicalize
// sign (largest |entry| positive); write output.
__global__ __launch_bounds__(512) void k_backtransform(const float* M, const float* tauA,
                                                       const float* vtri, float* out) {
    int b = blockIdx.x;
    int pass = blockIdx.y;
    int w = threadIdx.x >> 6;
    int lane = threadIdx.x & 63;
    int j = pass * 8 + w;
    __shared__ float xs[8][NN];
    __shared__ float us[NN];
    const float* Mb = M + (int64_t)b * NN * NN;
    for (int i = lane; i < NN; i += 64)
        xs[w][i] = vtri[((int64_t)b * NLOW + j) * NN + i];
    __syncthreads();
    for (int k = NN - 3; k >= 0; --k) {
        int m = NN - 1 - k;
        for (int t = threadIdx.x; t < (unsigned)m; t += 512)
            us[t] = Mb[(int64_t)(k + 1 + t) * NN + k];
        __syncthreads();
        float tauk = tauA[b * NN + k];
        float acc = 0.f;
        for (int t = lane; t < m; t += 64) acc += us[t] * xs[w][k + 1 + t];
        for (int off = 32; off > 0; off >>= 1) acc += __shfl_xor(acc, off);
        float s = tauk * acc;
        for (int t = lane; t < m; t += 64) xs[w][k + 1 + t] -= s * us[t];
        __syncthreads();
    }
    float mx = -1.f; int mi = 0;
    for (int i = lane; i < NN; i += 64) {
        float a = fabsf(xs[w][i]);
        if (a > mx) { mx = a; mi = i; }
    }
    for (int off = 32; off > 0; off >>= 1) {
        float omx = __shfl_xor(mx, off);
        int omi = __shfl_xor(mi, off);
        if (omx > mx || (omx == mx && omi < mi)) { mx = omx; mi = omi; }
    }
    float sgn = (xs[w][mi] < 0.f) ? -1.f : 1.f;
    for (int i = lane; i < NN; i += 64)
        out[256 + ((int64_t)(b * NN + i)) * NLOW + j] = sgn * xs[w][i];
}

// ---------------------------------------------------------------------------
extern "C" void kernel_launch(void* const* d_in, const int* in_sizes, int n_in,
                              void* d_out, int out_size, void* d_ws, size_t ws_size,
                              hipStream_t stream) {
    const float* A = (const float*)d_in[0];
    float* out = (float*)d_out;

    char* base = (char*)d_ws;
    size_t off = 0;
    auto alloc = [&](size_t bytes) -> void* {
        void* p = (void*)(base + off);
        off = (off + bytes + 255) & ~(size_t)255;
        return p;
    };
    double* lam  = (double*)alloc(sizeof(double) * NB * NLOW);
    double* u0   = (double*)alloc(sizeof(double) * (size_t)NB * NLOW * NN);
    double* u1   = (double*)alloc(sizeof(double) * (size_t)NB * NLOW * NN);
    double* u2   = (double*)alloc(sizeof(double) * (size_t)NB * NLOW * NN);
    double* lmul = (double*)alloc(sizeof(double) * (size_t)NB * NLOW * NN);
    double* xv   = (double*)alloc(sizeof(double) * (size_t)NB * NLOW * NN);
    float* pivf  = (float*)alloc(sizeof(float) * (size_t)NB * NLOW * NN);
    float* vtri  = (float*)alloc(sizeof(float) * (size_t)NB * NLOW * NN);
    float* tau   = (float*)alloc(sizeof(float) * NB * NN);
    float* evec  = (float*)alloc(sizeof(float) * NB * NN);
    float* dvec  = (float*)alloc(sizeof(float) * NB * NN);
    float* wv    = (float*)alloc(sizeof(float) * NB * NN);
    float* Vp    = (float*)alloc(sizeof(float) * (size_t)NB * PNB * NN);
    float* Wp    = (float*)alloc(sizeof(float) * (size_t)NB * PNB * NN);
    size_t small_end = off;

    float* M;
    if (ws_size >= small_end + sizeof(float) * (size_t)NB * NN * NN)
        M = (float*)alloc(sizeof(float) * (size_t)NB * NN * NN);
    else
        M = (float*)d_in[0];   // in-place fallback (harness restores d_in)

    int grid_sym = (NB * NN * NN) / 256;
    k_symmetrize<<<grid_sym, 256, 0, stream>>>(A, M);

    for (int k0 = 0; k0 < NN - 2; k0 += PNB) {
        int jmax = NN - 2 - k0; if (jmax > PNB) jmax = PNB;
        for (int j = 0; j < jmax; ++j) {
            k_panel<<<NB, 256, 0, stream>>>(M, Vp, Wp, wv, tau, evec, dvec, k0, j, 1);
            int k = k0 + j, m = NN - 1 - k;
            dim3 g(NB, (unsigned)((m + 255) / 256), (unsigned)((m + JCH - 1) / JCH));
            k_symv<<<g, 256, 0, stream>>>(M, Vp, wv, k0, j);
        }
        // finish last W column of the panel (no new reflector)
        k_panel<<<NB, 256, 0, stream>>>(M, Vp, Wp, wv, tau, evec, dvec, k0, jmax, 0);
        int s = k0 + jmax, m2 = NN - s;
        if (m2 > 0) {
            dim3 gu(NB, (unsigned)((m2 + 63) / 64), (unsigned)((m2 + 63) / 64));
            k_update<<<gu, 256, 0, stream>>>(M, Vp, Wp, k0, jmax);
        }
    }

    k_extract2<<<NB, 64, 0, stream>>>(M, dvec, evec);
    k_bisect<<<1, 256, 0, stream>>>(dvec, evec, lam, out);
    k_invit<<<4, 64, 0, stream>>>(dvec, evec, lam, vtri, u0, u1, u2, lmul, pivf, xv);
    k_gs<<<NB, 256, 0, stream>>>(vtri);
    dim3 gI(NB, 2);
    k_backtransform<<<gI, 512, 0, stream>>>(M, tau, vtri, out);
}

// Round 3
// 41041.217 us; speedup vs baseline: 3.0599x; 1.4771x over previous
//
#include <hip/hip_runtime.h>
#include <stdint.h>
#include <math.h>

#define NN 1024
#define NB 16
#define NLOW 16
#define PNB 32      // panel width
#define JCH 128     // symv col-chunk
#define GMID 4      // blocks per batch for midA/midB

// ---------------------------------------------------------------------------
// Unscaled-reflector scalars from (alpha, norm2_rest):
//   beta = -sign(a)*sqrt(a^2+rest);  u0 = a - beta;  taut = -1/(beta*(a-beta))
__device__ inline void patchvals(float alphaf, double rest, float& albe, float& beta, float& taut) {
    if (rest == 0.0) { albe = 0.f; beta = alphaf; taut = 0.f; return; }
    double a = (double)alphaf;
    double nrm = sqrt(a * a + rest);
    double b = (a >= 0.0) ? -nrm : nrm;
    double ab = a - b;
    albe = (float)ab;
    beta = (float)b;
    taut = (float)(-1.0 / (b * ab));
}

// ---------------------------------------------------------------------------
__global__ void k_symmetrize(const float* A, float* M) {
    int64_t t = (int64_t)blockIdx.x * blockDim.x + threadIdx.x;
    if (t >= (int64_t)NB * NN * NN) return;
    int b = (int)(t / (NN * NN));
    int rc = (int)(t % (NN * NN));
    int r = rc / NN, c = rc % NN;
    if (r > c) return;
    const float* Ab = A + (int64_t)b * NN * NN;
    float s = 0.5f * (Ab[(int64_t)r * NN + c] + Ab[(int64_t)c * NN + r]);
    float* Mb = M + (int64_t)b * NN * NN;
    Mb[(int64_t)r * NN + c] = s;
    Mb[(int64_t)c * NN + r] = s;
}

__global__ void k_zeroinit(float* wv, double* norm2A, double* dotwA) {
    int t = blockIdx.x * 256 + threadIdx.x;
    if (t < NB * NN) { wv[t] = 0.f; norm2A[t] = 0.0; dotwA[t] = 0.0; }
}

// ---------------------------------------------------------------------------
// midA(j): finalize Wbar'_{j-1} = taut*(wraw - sum_{t<j-1}[u_t*g1 + w'_t*g2]),
// accumulate dotw = Wbar'^T u. Also zero wv for the next symv.
__global__ __launch_bounds__(256) void k_midA(const float* Vp, float* Wp, float* wv,
                                              const float* tauA, double* dotwA,
                                              const double* c1A, const double* c2A,
                                              int k0, int j) {
    int b = blockIdx.x, y = blockIdx.y, tid = threadIdx.x;
    int jp = j - 1, kp = k0 + jp, m0 = NN - 1 - k0;
    __shared__ float g1[PNB], g2[PNB];
    __shared__ double redd[256];
    if (tid < jp) {
        double kap = 0.5 * (double)tauA[b * NN + k0 + tid] * dotwA[b * NN + k0 + tid];
        double c2 = c2A[b * PNB + tid];
        g1[tid] = (float)(c1A[b * PNB + tid] - 2.0 * kap * c2);
        g2[tid] = (float)c2;
    }
    __syncthreads();
    float taut = tauA[b * NN + kp];
    const float* ujp = Vp + ((int64_t)b * PNB + jp) * NN;
    float* wcol = Wp + ((int64_t)b * PNB + jp) * NN;
    double dacc = 0.0;
    for (int i = jp + y * 256 + tid; i < m0; i += GMID * 256) {
        float wr = wv[b * NN + i];
        wv[b * NN + i] = 0.f;
        for (int t = 0; t < jp; ++t)
            wr -= Vp[((int64_t)b * PNB + t) * NN + i] * g1[t]
                + Wp[((int64_t)b * PNB + t) * NN + i] * g2[t];
        float wf = taut * wr;
        wcol[i] = wf;
        dacc += (double)wf * (double)ujp[i];
    }
    redd[tid] = dacc; __syncthreads();
    for (int s = 128; s > 0; s >>= 1) {
        if (tid < s) redd[tid] += redd[tid + s];
        __syncthreads();
    }
    if (tid == 0) atomicAdd(&dotwA[b * NN + kp], redd[0]);
}

// ---------------------------------------------------------------------------
// midB(j): update column k=k0+j with the j finished pairs (kappa on the fly),
// write u (unscaled, unpatched) to Vp col j and M col k, diag d_k,
// alpha = u[row j], atomic norm2 over rest.
__global__ __launch_bounds__(256) void k_midB(float* M, float* Vp, const float* Wp,
                                              float* dA, const float* tauA, const double* dotwA,
                                              double* norm2A, float* alphaA,
                                              int k0, int j) {
    int b = blockIdx.x, y = blockIdx.y, tid = threadIdx.x;
    int k = k0 + j, m0 = NN - 1 - k0;
    float* Mb = M + (int64_t)b * NN * NN;
    __shared__ float h1[PNB], h2[PNB], h3[PNB];
    __shared__ double redd[256];
    if (tid < j) {
        int r = j - 1;
        float ur = Vp[((int64_t)b * PNB + tid) * NN + r];
        float wr = Wp[((int64_t)b * PNB + tid) * NN + r];
        float kap = (float)(0.5 * (double)tauA[b * NN + k0 + tid] * dotwA[b * NN + k0 + tid]);
        float wbar = wr - kap * ur;       // Wbar_t[r]
        h1[tid] = wbar - kap * ur;        // coefficient on u_t[i]
        h2[tid] = ur;                     // coefficient on w'_t[i]
        h3[tid] = ur * wbar;              // for diagonal
    }
    __syncthreads();
    if (y == 0 && tid == 0) {
        float dk = Mb[(int64_t)k * NN + k];
        for (int t = 0; t < j; ++t) dk -= 2.f * h3[t];
        dA[b * NN + k] = dk;
    }
    double nacc = 0.0;
    float* ucol = Vp + ((int64_t)b * PNB + j) * NN;
    for (int i = j + y * 256 + tid; i < m0; i += GMID * 256) {
        float x = Mb[(int64_t)(k0 + 1 + i) * NN + k];
        for (int t = 0; t < j; ++t)
            x -= Vp[((int64_t)b * PNB + t) * NN + i] * h1[t]
               + Wp[((int64_t)b * PNB + t) * NN + i] * h2[t];
        ucol[i] = x;
        Mb[(int64_t)(k0 + 1 + i) * NN + k] = x;
        if (i == j) alphaA[b * NN + k] = x;
        else nacc += (double)x * (double)x;
    }
    redd[tid] = nacc; __syncthreads();
    for (int s = 128; s > 0; s >>= 1) {
        if (tid < s) redd[tid] += redd[tid + s];
        __syncthreads();
    }
    if (tid == 0) atomicAdd(&norm2A[b * NN + k], redd[0]);
}

// ---------------------------------------------------------------------------
// symv(j): wraw += A(k+1:,k+1:)*u_j (chunked, atomics). Extra y-blocks compute
// c1raw[t]=w'_t^T u_j, c2[t]=u_t^T u_j. One thread patches u[0]=alpha-beta in
// global (Vp + M column), writes e_k=beta, tau_k=taut. All readers of the
// patched element substitute the computed value -> race-immune.
__global__ __launch_bounds__(256) void k_symv(float* M, float* Vp, const float* Wp,
                                              float* wv, float* tauA, float* eA,
                                              const float* alphaA, const double* norm2A,
                                              double* c1A, double* c2A,
                                              int k0, int j, int nr, int nc) {
    int b = blockIdx.x, y = blockIdx.y, tid = threadIdx.x;
    int k = k0 + j, m = NN - 1 - k, base = k + 1, m0 = NN - 1 - k0;
    float albe, beta, taut;
    patchvals(alphaA[b * NN + k], norm2A[b * NN + k], albe, beta, taut);
    float* Mb = M + (int64_t)b * NN * NN;
    float* ucol = Vp + ((int64_t)b * PNB + j) * NN;
    __shared__ float vs[JCH];
    __shared__ double r1[256], r2[256];
    if (y < nr * nc) {
        if (y == 0 && tid == 0) {
            ucol[j] = albe;
            Mb[(int64_t)(k0 + 1 + j) * NN + k] = albe;
            eA[b * NN + k] = beta;
            tauA[b * NN + k] = taut;
        }
        int ir = y % nr, ic = y / nr;
        int i = ir * 256 + tid;
        int jg0 = ic * JCH, jg1 = min(m, jg0 + JCH);
        for (int t = tid; t < jg1 - jg0; t += 256) vs[t] = ucol[jg0 + t + j];
        __syncthreads();
        if (tid == 0 && jg0 == 0) vs[0] = albe;
        __syncthreads();
        if (i < m) {
            const float* p = Mb + (int64_t)(base + jg0) * NN + base + i;
            float acc = 0.f;
            for (int jg = jg0; jg < jg1; ++jg, p += NN) acc += (*p) * vs[jg - jg0];
            atomicAdd(&wv[b * NN + i + j], acc);
        }
    } else {
        int t = y - nr * nc;   // t < j
        const float* ut = Vp + ((int64_t)b * PNB + t) * NN;
        const float* wt = Wp + ((int64_t)b * PNB + t) * NN;
        double a1 = 0.0, a2 = 0.0;
        for (int i = j + tid; i < m0; i += 256) {
            float uj = (i == j) ? albe : ucol[i];
            a1 += (double)wt[i] * (double)uj;
            a2 += (double)ut[i] * (double)uj;
        }
        r1[tid] = a1; r2[tid] = a2; __syncthreads();
        for (int s = 128; s > 0; s >>= 1) {
            if (tid < s) { r1[tid] += r1[tid + s]; r2[tid] += r2[tid + s]; }
            __syncthreads();
        }
        if (tid == 0) { c1A[b * PNB + t] = r1[0]; c2A[b * PNB + t] = r2[0]; }
    }
}

// ---------------------------------------------------------------------------
// Trailing update A(s:,s:) -= U*Wbar^T + Wbar*U^T with Wbar = w' - kappa*u.
__global__ __launch_bounds__(256) void k_update(float* M, const float* Vp, const float* Wp,
                                                const float* tauA, const double* dotwA,
                                                int k0, int nbe) {
    int b = blockIdx.x;
    int s = k0 + nbe, m2 = NN - s;
    int r0 = blockIdx.y * 64, c0 = blockIdx.z * 64;
    if (r0 >= m2 || c0 >= m2) return;
    __shared__ float Vr[PNB][64], Wr[PNB][64], Vc[PNB][64], Wc[PNB][64];
    __shared__ float kap[PNB];
    int tid = threadIdx.x;
    if (tid < nbe)
        kap[tid] = (float)(0.5 * (double)tauA[b * NN + k0 + tid] * dotwA[b * NN + k0 + tid]);
    __syncthreads();
    int rowoff = nbe - 1;
    for (int idx = tid; idx < nbe * 64; idx += 256) {
        int t = idx >> 6, x = idx & 63;
        const float* vp = Vp + ((int64_t)b * PNB + t) * NN;
        const float* wp = Wp + ((int64_t)b * PNB + t) * NN;
        int rr = r0 + x, cc = c0 + x;
        float vr = (rr < m2) ? vp[rowoff + rr] : 0.f;
        float wr = (rr < m2) ? wp[rowoff + rr] : 0.f;
        float vc = (cc < m2) ? vp[rowoff + cc] : 0.f;
        float wc = (cc < m2) ? wp[rowoff + cc] : 0.f;
        Vr[t][x] = vr; Wr[t][x] = wr - kap[t] * vr;
        Vc[t][x] = vc; Wc[t][x] = wc - kap[t] * vc;
    }
    __syncthreads();
    int tx = tid & 15, ty = tid >> 4;
    float accv[4][4] = {};
    for (int t = 0; t < nbe; ++t) {
        float va[4], wa[4], vb4[4], wb4[4];
#pragma unroll
        for (int a = 0; a < 4; ++a) {
            va[a] = Vr[t][ty * 4 + a]; wa[a] = Wr[t][ty * 4 + a];
            vb4[a] = Vc[t][tx * 4 + a]; wb4[a] = Wc[t][tx * 4 + a];
        }
#pragma unroll
        for (int a = 0; a < 4; ++a)
#pragma unroll
            for (int c = 0; c < 4; ++c) accv[a][c] += va[a] * wb4[c] + wa[a] * vb4[c];
    }
    float* Mb = M + (int64_t)b * NN * NN;
    for (int a = 0; a < 4; ++a) {
        int r = r0 + ty * 4 + a;
        if (r >= m2) break;
        for (int c = 0; c < 4; ++c) {
            int cc = c0 + tx * 4 + c;
            if (cc >= m2) continue;
            Mb[(int64_t)(s + r) * NN + (s + cc)] -= accv[a][c];
        }
    }
}

// ---------------------------------------------------------------------------
__global__ void k_extract2(const float* M, float* dA, float* eA) {
    int b = blockIdx.x;
    if (threadIdx.x == 0) {
        const float* Mb = M + (int64_t)b * NN * NN;
        dA[b * NN + NN - 2] = Mb[(int64_t)(NN - 2) * NN + NN - 2];
        dA[b * NN + NN - 1] = Mb[(int64_t)(NN - 1) * NN + NN - 1];
        eA[b * NN + NN - 2] = Mb[(int64_t)(NN - 1) * NN + NN - 2];
    }
}

// ---------------------------------------------------------------------------
__global__ void k_bisect(const float* dA, const float* eA, double* lam, float* out) {
    int p = threadIdx.x;
    int b = p >> 4, j = p & 15;
    const float* d = dA + b * NN;
    const float* e = eA + b * NN;
    double lo = 1e30, hi = -1e30;
    for (int i = 0; i < NN; ++i) {
        double di = (double)d[i];
        double r = 0.0;
        if (i > 0) r += fabs((double)e[i - 1]);
        if (i < NN - 1) r += fabs((double)e[i]);
        lo = fmin(lo, di - r);
        hi = fmax(hi, di + r);
    }
    lo -= 1e-3; hi += 1e-3;
    for (int it = 0; it < 50; ++it) {
        double x = 0.5 * (lo + hi);
        int cnt = 0;
        double q = (double)d[0] - x;
        if (q < 0.0) cnt++;
        for (int i = 1; i < NN; ++i) {
            double ei = (double)e[i - 1];
            double den = q;
            if (fabs(den) < 1e-30) den = (den < 0.0) ? -1e-30 : 1e-30;
            q = ((double)d[i] - x) - ei * ei / den;
            if (q < 0.0) cnt++;
        }
        if (cnt >= j + 1) hi = x; else lo = x;
    }
    double l = 0.5 * (lo + hi);
    lam[p] = l;
    out[b * NLOW + j] = (float)l;
}

// ---------------------------------------------------------------------------
__global__ void k_invit(const float* dA, const float* eA, const double* lam,
                        float* vtri, double* U0, double* U1, double* U2,
                        double* LM, float* PV, double* XV) {
    int p = blockIdx.x * blockDim.x + threadIdx.x;
    if (p >= NB * NLOW) return;
    int b = p / NLOW;
    const float* d = dA + b * NN;
    const float* e = eA + b * NN;
    double lambda = lam[p];
    double* dd  = U0 + (int64_t)p * NN;
    double* du  = U1 + (int64_t)p * NN;
    double* du2 = U2 + (int64_t)p * NN;
    double* dl  = LM + (int64_t)p * NN;
    float*  pv  = PV + (int64_t)p * NN;
    double* X   = XV + (int64_t)p * NN;

    for (int i = 0; i < NN; ++i) dd[i] = (double)d[i] - lambda;
    for (int i = 0; i < NN - 1; ++i) { du[i] = (double)e[i]; dl[i] = (double)e[i]; }
    du[NN - 1] = 0.0; dl[NN - 1] = 0.0;

    for (int i = 0; i < NN - 1; ++i) {
        if (fabs(dd[i]) >= fabs(dl[i])) {
            pv[i] = 0.f;
            double fact = (dd[i] != 0.0) ? dl[i] / dd[i] : 0.0;
            dl[i] = fact;
            dd[i + 1] -= fact * du[i];
            du2[i] = 0.0;
        } else {
            pv[i] = 1.f;
            double fact = dd[i] / dl[i];
            dd[i] = dl[i];
            dl[i] = fact;
            double temp = du[i];
            du[i] = dd[i + 1];
            dd[i + 1] = temp - fact * dd[i + 1];
            if (i < NN - 2) { du2[i] = du[i + 1]; du[i + 1] = -fact * du[i + 1]; }
            else du2[i] = 0.0;
        }
    }
    for (int i = 0; i < NN; ++i)
        if (fabs(dd[i]) < 1e-300) dd[i] = (dd[i] < 0.0) ? -1e-300 : 1e-300;

    for (int i = 0; i < NN; ++i) {
        uint32_t h = ((uint32_t)i * 2654435761u) ^ ((uint32_t)p * 40503u);
        h = h * 1664525u + 1013904223u;
        X[i] = 1.0 + 1e-3 * ((double)(h & 2047) / 1024.0 - 1.0);
    }
    for (int iter = 0; iter < 2; ++iter) {
        for (int i = 0; i < NN - 1; ++i) {
            if (pv[i] == 0.f) X[i + 1] -= dl[i] * X[i];
            else { double t = X[i]; X[i] = X[i + 1]; X[i + 1] = t - dl[i] * X[i]; }
        }
        X[NN - 1] /= dd[NN - 1];
        X[NN - 2] = (X[NN - 2] - du[NN - 2] * X[NN - 1]) / dd[NN - 2];
        for (int i = NN - 3; i >= 0; --i)
            X[i] = (X[i] - du[i] * X[i + 1] - du2[i] * X[i + 2]) / dd[i];
        double nrm = 0.0;
        for (int i = 0; i < NN; ++i) nrm += X[i] * X[i];
        double inv = 1.0 / sqrt(fmax(nrm, 1e-300));
        for (int i = 0; i < NN; ++i) X[i] *= inv;
    }
    float* vt = vtri + (int64_t)p * NN;
    for (int i = 0; i < NN; ++i) vt[i] = (float)X[i];
}

// ---------------------------------------------------------------------------
__global__ void k_gs(float* vtri) {
    int b = blockIdx.x;
    float* V = vtri + (int64_t)b * NLOW * NN;
    __shared__ double red[256];
    for (int j = 0; j < NLOW; ++j) {
        float* vj = V + j * NN;
        for (int i2 = 0; i2 < j; ++i2) {
            const float* vi = V + i2 * NN;
            double acc = 0.0;
            for (int t = threadIdx.x; t < NN; t += 256) acc += (double)vi[t] * (double)vj[t];
            red[threadIdx.x] = acc; __syncthreads();
            for (int s = 128; s > 0; s >>= 1) {
                if ((int)threadIdx.x < s) red[threadIdx.x] += red[threadIdx.x + s];
                __syncthreads();
            }
            float r = (float)red[0];
            for (int t = threadIdx.x; t < NN; t += 256) vj[t] -= r * vi[t];
            __syncthreads();
        }
        double acc = 0.0;
        for (int t = threadIdx.x; t < NN; t += 256) acc += (double)vj[t] * (double)vj[t];
        red[threadIdx.x] = acc; __syncthreads();
        for (int s = 128; s > 0; s >>= 1) {
            if ((int)threadIdx.x < s) red[threadIdx.x] += red[threadIdx.x + s];
            __syncthreads();
        }
        float inv = (float)(1.0 / sqrt(fmax(red[0], 1e-300)));
        for (int t = threadIdx.x; t < NN; t += 256) vj[t] *= inv;
        __syncthreads();
    }
}

// ---------------------------------------------------------------------------
// Back-transform: H_k = I - taut_k * u_k u_k^T, applied k = NN-3 .. 0.
__global__ __launch_bounds__(512) void k_backtransform(const float* M, const float* tauA,
                                                       const float* vtri, float* out) {
    int b = blockIdx.x;
    int pass = blockIdx.y;
    int w = threadIdx.x >> 6;
    int lane = threadIdx.x & 63;
    int j = pass * 8 + w;
    __shared__ float xs[8][NN];
    __shared__ float us[NN];
    const float* Mb = M + (int64_t)b * NN * NN;
    for (int i = lane; i < NN; i += 64)
        xs[w][i] = vtri[((int64_t)b * NLOW + j) * NN + i];
    __syncthreads();
    for (int k = NN - 3; k >= 0; --k) {
        int m = NN - 1 - k;
        for (int t = threadIdx.x; t < (unsigned)m; t += 512)
            us[t] = Mb[(int64_t)(k + 1 + t) * NN + k];
        __syncthreads();
        float tauk = tauA[b * NN + k];
        float acc = 0.f;
        for (int t = lane; t < m; t += 64) acc += us[t] * xs[w][k + 1 + t];
        for (int off = 32; off > 0; off >>= 1) acc += __shfl_xor(acc, off);
        float s = tauk * acc;
        for (int t = lane; t < m; t += 64) xs[w][k + 1 + t] -= s * us[t];
        __syncthreads();
    }
    float mx = -1.f; int mi = 0;
    for (int i = lane; i < NN; i += 64) {
        float a = fabsf(xs[w][i]);
        if (a > mx) { mx = a; mi = i; }
    }
    for (int off = 32; off > 0; off >>= 1) {
        float omx = __shfl_xor(mx, off);
        int omi = __shfl_xor(mi, off);
        if (omx > mx || (omx == mx && omi < mi)) { mx = omx; mi = omi; }
    }
    float sgn = (xs[w][mi] < 0.f) ? -1.f : 1.f;
    for (int i = lane; i < NN; i += 64)
        out[256 + ((int64_t)(b * NN + i)) * NLOW + j] = sgn * xs[w][i];
}

// ---------------------------------------------------------------------------
extern "C" void kernel_launch(void* const* d_in, const int* in_sizes, int n_in,
                              void* d_out, int out_size, void* d_ws, size_t ws_size,
                              hipStream_t stream) {
    const float* A = (const float*)d_in[0];
    float* out = (float*)d_out;

    char* base = (char*)d_ws;
    size_t off = 0;
    auto alloc = [&](size_t bytes) -> void* {
        void* p = (void*)(base + off);
        off = (off + bytes + 255) & ~(size_t)255;
        return p;
    };
    double* lam  = (double*)alloc(sizeof(double) * NB * NLOW);
    double* u0   = (double*)alloc(sizeof(double) * (size_t)NB * NLOW * NN);
    double* u1   = (double*)alloc(sizeof(double) * (size_t)NB * NLOW * NN);
    double* u2   = (double*)alloc(sizeof(double) * (size_t)NB * NLOW * NN);
    double* lmul = (double*)alloc(sizeof(double) * (size_t)NB * NLOW * NN);
    double* xv   = (double*)alloc(sizeof(double) * (size_t)NB * NLOW * NN);
    float* pivf  = (float*)alloc(sizeof(float) * (size_t)NB * NLOW * NN);
    float* vtri  = (float*)alloc(sizeof(float) * (size_t)NB * NLOW * NN);
    float* tau   = (float*)alloc(sizeof(float) * NB * NN);
    float* evec  = (float*)alloc(sizeof(float) * NB * NN);
    float* dvec  = (float*)alloc(sizeof(float) * NB * NN);
    float* wv    = (float*)alloc(sizeof(float) * NB * NN);
    float* alphaA = (float*)alloc(sizeof(float) * NB * NN);
    double* norm2A = (double*)alloc(sizeof(double) * NB * NN);
    double* dotwA  = (double*)alloc(sizeof(double) * NB * NN);
    double* c1A    = (double*)alloc(sizeof(double) * NB * PNB);
    double* c2A    = (double*)alloc(sizeof(double) * NB * PNB);
    float* Vp    = (float*)alloc(sizeof(float) * (size_t)NB * PNB * NN);
    float* Wp    = (float*)alloc(sizeof(float) * (size_t)NB * PNB * NN);
    size_t small_end = off;

    float* M;
    if (ws_size >= small_end + sizeof(float) * (size_t)NB * NN * NN)
        M = (float*)alloc(sizeof(float) * (size_t)NB * NN * NN);
    else
        M = (float*)d_in[0];   // in-place fallback (harness restores d_in)

    int grid_sym = (NB * NN * NN) / 256;
    k_symmetrize<<<grid_sym, 256, 0, stream>>>(A, M);
    k_zeroinit<<<(NB * NN + 255) / 256, 256, 0, stream>>>(wv, norm2A, dotwA);

    for (int k0 = 0; k0 < NN - 2; k0 += PNB) {
        int jmax = NN - 2 - k0; if (jmax > PNB) jmax = PNB;
        for (int j = 0; j < jmax; ++j) {
            if (j > 0)
                k_midA<<<dim3(NB, GMID), 256, 0, stream>>>(Vp, Wp, wv, tau, dotwA, c1A, c2A, k0, j);
            k_midB<<<dim3(NB, GMID), 256, 0, stream>>>(M, Vp, Wp, dvec, tau, dotwA, norm2A, alphaA, k0, j);
            int k = k0 + j, m = NN - 1 - k;
            int nr = (m + 255) / 256, nc = (m + JCH - 1) / JCH;
            k_symv<<<dim3(NB, nr * nc + j), 256, 0, stream>>>(M, Vp, Wp, wv, tau, evec,
                                                              alphaA, norm2A, c1A, c2A,
                                                              k0, j, nr, nc);
        }
        k_midA<<<dim3(NB, GMID), 256, 0, stream>>>(Vp, Wp, wv, tau, dotwA, c1A, c2A, k0, jmax);
        int s = k0 + jmax, m2 = NN - s;
        if (m2 > 0) {
            dim3 gu(NB, (unsigned)((m2 + 63) / 64), (unsigned)((m2 + 63) / 64));
            k_update<<<gu, 256, 0, stream>>>(M, Vp, Wp, tau, dotwA, k0, jmax);
        }
    }

    k_extract2<<<NB, 64, 0, stream>>>(M, dvec, evec);
    k_bisect<<<1, 256, 0, stream>>>(dvec, evec, lam, out);
    k_invit<<<4, 64, 0, stream>>>(dvec, evec, lam, vtri, u0, u1, u2, lmul, pivf, xv);
    k_gs<<<NB, 256, 0, stream>>>(vtri);
    dim3 gI(NB, 2);
    k_backtransform<<<gI, 512, 0, stream>>>(M, tau, vtri, out);
}